// Round 3
// baseline (154.595 us; speedup 1.0000x reference)
//
#include <hip/hip_runtime.h>
#include <hip/hip_bf16.h>
#include <stdint.h>

#define VOCAB 100000
#define SEQ   8192
#define BATCH 8
#define DIM   128

#define WLT_BLOCKS 1563          // ceil(100000/64)
#define WCONV_BLOCKS 320         // 5*128*128 / 256

typedef short bf16x8 __attribute__((ext_vector_type(8)));
typedef float f32x4  __attribute__((ext_vector_type(4)));

__device__ __forceinline__ ushort f2bf(float f) {
  union { float f; uint32_t u; } v; v.f = f;
  uint32_t u = v.u;
  return (ushort)((u + 0x7FFF + ((u >> 16) & 1)) >> 16);  // RNE; inputs never NaN
}

// ---------------------------------------------------------------------------
// Prep kernel (merged): blocks [0, WLT_BLOCKS) build wlt via LDS tile
// transpose; blocks [WLT_BLOCKS, +320) repack W_conv (d,i,k)->wcb[k][d][i].
// ---------------------------------------------------------------------------
__global__ __launch_bounds__(256) void prep(
    const float* __restrict__ wlin, const float* __restrict__ blin,
    const float* __restrict__ wconv, ushort* __restrict__ wlt,
    ushort* __restrict__ wcb) {
  __shared__ float tile[128 * 65];
  const int tid = threadIdx.x;

  if (blockIdx.x >= WLT_BLOCKS) {
    int e = (blockIdx.x - WLT_BLOCKS) * 256 + tid;   // < 81920
    int k = e / (DIM * DIM);
    int rem = e % (DIM * DIM);
    int d = rem / DIM, i = rem % DIM;
    wcb[e] = f2bf(wconv[(d * DIM + i) * 5 + k]);
    return;
  }

  const int t0 = blockIdx.x * 64;

  // Phase A: float4 coalesced reads of W_lin rows into fp32 LDS tile.
  const int c4 = (tid & 15) * 4;
  const int rbase = tid >> 4;
  const bool cvalid = (t0 + c4) < VOCAB;   // VOCAB%4==0 -> whole float4 ok
#pragma unroll
  for (int p = 0; p < 8; ++p) {
    int r = p * 16 + rbase;
    float4 v = make_float4(0.f, 0.f, 0.f, 0.f);
    if (cvalid) v = *(const float4*)(wlin + (size_t)r * VOCAB + t0 + c4);
    float* dst = &tile[r * 65 + c4];
    dst[0] = v.x; dst[1] = v.y; dst[2] = v.z; dst[3] = v.w;
  }
  __syncthreads();

  // Phase B: transposed reads (+bias), bf16 pack, contiguous 1KB/wave stores.
  const int chunk = tid & 15;
  float bias8[8];
#pragma unroll
  for (int j = 0; j < 8; ++j) bias8[j] = blin[chunk * 8 + j];

#pragma unroll
  for (int p = 0; p < 4; ++p) {
    int tl = (tid >> 4) + p * 16;
    int t  = t0 + tl;
    if (t >= VOCAB) continue;
    ushort u[8];
#pragma unroll
    for (int j = 0; j < 8; ++j)
      u[j] = f2bf(tile[(chunk * 8 + j) * 65 + tl] + bias8[j]);
    *(uint4*)(wlt + (size_t)t * DIM + chunk * 8) = *(const uint4*)u;
  }
}

// ---------------------------------------------------------------------------
// Main: per block: 64 positions x 128 out-channels (1024 blocks -> 4+/CU
// co-resident for gather-latency hiding).
// LDS A-tile: 68 emb rows (halo +-2) x 128 bf16, pitch 136 ushorts.
// Conv tap k == A-tile row shift k: 5 accumulated K=128 GEMMs, one staging.
// B frags loaded from wcb (L2-hot) inside the kk loop (16 live VGPRs).
// ---------------------------------------------------------------------------
__global__ __launch_bounds__(256, 4) void conv_main(
    const int* __restrict__ X, const ushort* __restrict__ wlt,
    const ushort* __restrict__ wcb, const float* __restrict__ bconv,
    const float* __restrict__ pos, float* __restrict__ out) {
  __shared__ __align__(16) ushort Atile[68 * 136];

  const int tid   = threadIdx.x;
  const int bm    = blockIdx.x;                 // 0..1023
  const int batch = bm >> 7;
  const int nbase = (bm & 127) << 6;
  const int* Xb   = X + batch * SEQ;

  // ---- stage A: 68 rows x 16 chunks of 16B (1088 chunks, 5 iters) ----
  int  tok[5];
  bool valid[5];
#pragma unroll
  for (int it = 0; it < 5; ++it) {
    int c = tid + it * 256;
    int r = c >> 4;
    int n = nbase - 2 + r;
    bool v = (c < 1088) && (n >= 0) && (n < SEQ);
    valid[it] = v;
    tok[it] = v ? Xb[n] : 0;
  }
  uint4 val[5];
#pragma unroll
  for (int it = 0; it < 5; ++it) {
    int ch = (tid + it * 256) & 15;
    val[it] = valid[it] ? *(const uint4*)(wlt + (size_t)tok[it] * DIM + ch * 8)
                        : make_uint4(0u, 0u, 0u, 0u);
  }
#pragma unroll
  for (int it = 0; it < 5; ++it) {
    int c = tid + it * 256;
    if (c < 1088) {
      int r = c >> 4, ch = c & 15;
      *(uint4*)&Atile[r * 136 + ch * 8] = val[it];
    }
  }
  __syncthreads();

  // ---- compute: 4 waves, each 32x64 = 2x4 frags of 16x16x32 bf16 ----
  const int wave = tid >> 6;
  const int lane = tid & 63;
  const int wm = (wave >> 1) << 5;   // 0 or 32
  const int wn = (wave & 1) << 6;    // 0 or 64
  const int lr = lane & 15;
  const int lq = lane >> 4;

  f32x4 acc[2][4];
#pragma unroll
  for (int a = 0; a < 2; ++a)
#pragma unroll
    for (int b = 0; b < 4; ++b) acc[a][b] = (f32x4)0.f;

#pragma unroll
  for (int k = 0; k < 5; ++k) {
#pragma unroll
    for (int kk = 0; kk < 4; ++kk) {
      bf16x8 B[4];
#pragma unroll
      for (int nt = 0; nt < 4; ++nt)
        B[nt] = *(const bf16x8*)(wcb +
            ((size_t)(k * DIM + wn + nt * 16 + lr) * DIM + kk * 32 + lq * 8));
      bf16x8 A[2];
#pragma unroll
      for (int mt = 0; mt < 2; ++mt)
        A[mt] = *(const bf16x8*)&Atile[(wm + mt * 16 + lr + k) * 136 + kk * 32 + lq * 8];
#pragma unroll
      for (int mt = 0; mt < 2; ++mt)
#pragma unroll
        for (int nt = 0; nt < 4; ++nt)
          acc[mt][nt] = __builtin_amdgcn_mfma_f32_16x16x32_bf16(
              A[mt], B[nt], acc[mt][nt], 0, 0, 0);
    }
  }

  // ---- epilogue: + b_conv[d] + pos[n][d]; C layout col=lane&15, row=lq*4+rr ----
  float bc[4];
#pragma unroll
  for (int nt = 0; nt < 4; ++nt) bc[nt] = bconv[wn + nt * 16 + lr];
  float* outb = out + (size_t)batch * SEQ * DIM;
#pragma unroll
  for (int mt = 0; mt < 2; ++mt) {
#pragma unroll
    for (int rr = 0; rr < 4; ++rr) {
      int m = wm + mt * 16 + lq * 4 + rr;
      int gn = nbase + m;
      const float* posrow = pos + (size_t)gn * DIM;
      float* orow = outb + (size_t)gn * DIM;
#pragma unroll
      for (int nt = 0; nt < 4; ++nt) {
        int d = wn + nt * 16 + lr;
        orow[d] = acc[mt][nt][rr] + bc[nt] + posrow[d];
      }
    }
  }
}

// ---------------------------------------------------------------------------
extern "C" void kernel_launch(void* const* d_in, const int* in_sizes, int n_in,
                              void* d_out, int out_size, void* d_ws, size_t ws_size,
                              hipStream_t stream) {
  const int*   X     = (const int*)d_in[0];
  const float* wlin  = (const float*)d_in[1];
  const float* blin  = (const float*)d_in[2];
  const float* wconv = (const float*)d_in[3];
  const float* bconv = (const float*)d_in[4];
  const float* pos   = (const float*)d_in[5];
  float*       out   = (float*)d_out;

  ushort* wcb = (ushort*)d_ws;                       // 163,840 B
  ushort* wlt = (ushort*)((char*)d_ws + 262144);     // 25.6 MB

  hipLaunchKernelGGL(prep, dim3(WLT_BLOCKS + WCONV_BLOCKS), dim3(256), 0, stream,
                     wlin, blin, wconv, wlt, wcb);
  hipLaunchKernelGGL(conv_main, dim3(1024), dim3(256), 0, stream,
                     X, wlt, wcb, bconv, pos, out);
}